// Round 1
// baseline (217.557 us; speedup 1.0000x reference)
//
#include <hip/hip_runtime.h>
#include <math.h>

#define BATCH 256
#define FB    64
#define NCOL  147456   // 128*128*3*3
#define TPB   256
#define BT    32       // batch tile per block

#define FMA4(a, s, w) do { \
    (a).x = fmaf((s), (w).x, (a).x); \
    (a).y = fmaf((s), (w).y, (a).y); \
    (a).z = fmaf((s), (w).z, (a).z); \
    (a).w = fmaf((s), (w).w, (a).w); \
} while (0)

// One wave (64 lanes == FB) per batch row.
__global__ void softmax_rows(const float* __restrict__ x, float* __restrict__ p) {
    const int b = blockIdx.x;
    const int lane = threadIdx.x;
    float v = x[b * FB + lane];
    float m = v;
#pragma unroll
    for (int o = 32; o > 0; o >>= 1) m = fmaxf(m, __shfl_xor(m, o));
    float e = __expf(v - m);
    float s = e;
#pragma unroll
    for (int o = 32; o > 0; o >>= 1) s += __shfl_xor(s, o);
    p[b * FB + lane] = e / s;
}

// out[b][n] = sum_f probs[b][f] * W[f][n]
// Block: 256 threads x 4 cols (float4) = 1024 cols, 32-batch tile.
// Grid: (NCOL/1024, BATCH/BT) = (144, 8).
__global__ __launch_bounds__(TPB, 2) void bank_gemm(
        const float* __restrict__ W, const float* __restrict__ P,
        float* __restrict__ out) {
    __shared__ float pt[FB * BT];   // pt[f*BT + b]  (transposed probs tile)

    const int tid = threadIdx.x;
    const int bg  = blockIdx.y;

    // Stage probs tile transposed: coalesced global read, scattered LDS write
    // (one-off cost, negligible vs main loop).
    for (int i = tid; i < FB * BT; i += TPB) {
        const int f = i & (FB - 1);
        const int b = i >> 6;
        pt[f * BT + b] = P[bg * (FB * BT) + i];
    }
    __syncthreads();

    const int ncol4 = NCOL / 4;
    const float4* Wv = (const float4*)W;
    const int c4 = blockIdx.x * TPB + tid;   // this thread's float4 column

    float4 acc[BT];
#pragma unroll
    for (int b = 0; b < BT; ++b) acc[b] = make_float4(0.f, 0.f, 0.f, 0.f);

    // Main K loop with one-ahead weight prefetch.
    float4 w = Wv[c4];
    for (int f = 0; f < FB; ++f) {
        float4 wn = w;
        if (f + 1 < FB) wn = Wv[(f + 1) * ncol4 + c4];
        const float4* p4 = (const float4*)&pt[f * BT];
#pragma unroll
        for (int q = 0; q < BT / 4; ++q) {
            const float4 p = p4[q];   // uniform-address LDS broadcast
            FMA4(acc[4 * q + 0], p.x, w);
            FMA4(acc[4 * q + 1], p.y, w);
            FMA4(acc[4 * q + 2], p.z, w);
            FMA4(acc[4 * q + 3], p.w, w);
        }
        w = wn;
    }

    // Coalesced float4 stores.
    float4* Ov = (float4*)out;
    const long long obase = (long long)(bg * BT) * ncol4 + c4;
#pragma unroll
    for (int b = 0; b < BT; ++b) {
        Ov[obase + (long long)b * ncol4] = acc[b];
    }
}

extern "C" void kernel_launch(void* const* d_in, const int* in_sizes, int n_in,
                              void* d_out, int out_size, void* d_ws, size_t ws_size,
                              hipStream_t stream) {
    const float* bank   = (const float*)d_in[0];   // (256, 64)
    const float* weight = (const float*)d_in[1];   // (64, 128,128,3,3)
    float* out   = (float*)d_out;                  // (256, 147456)
    float* probs = (float*)d_ws;                   // 256*64 fp32 = 64 KB scratch

    softmax_rows<<<BATCH, FB, 0, stream>>>(bank, probs);

    dim3 grid(NCOL / (TPB * 4), BATCH / BT);
    bank_gemm<<<grid, TPB, 0, stream>>>(weight, probs, out);
}